// Round 10
// baseline (102.559 us; speedup 1.0000x reference)
//
#include <hip/hip_runtime.h>
#include <hip/hip_fp16.h>

// Clang native vector types — required by __builtin_nontemporal_* (HIP's
// float4/int4 are classes, which the builtin rejects).
typedef float vf4 __attribute__((ext_vector_type(4)));
typedef int   vi4 __attribute__((ext_vector_type(4)));

// Packed node record: path-segment sum s and jump pointer p in 8 bytes,
// so each random gather touches exactly one cache line.
struct SP { float s; int p; };

__device__ __forceinline__ SP ldSP(const SP* __restrict__ ptr) {
    float2 v = *reinterpret_cast<const float2*>(ptr);
    SP r; r.s = v.x; r.p = __float_as_int(v.y);
    return r;
}
__device__ __forceinline__ void stSP(SP* __restrict__ ptr, float s, int p) {
    float2 v; v.x = s; v.y = __int_as_float(p);
    *reinterpret_cast<float2*>(ptr) = v;
}

// levels -> fp16 table (4 MB, L2-resident) so contrib's random parent-level
// gathers stop missing. f32 source streamed nontemporally.
__global__ void k_lev16(const float* __restrict__ levels,
                        __half* __restrict__ lev, int N) {
    int stride = gridDim.x * blockDim.x;
    int n4 = N >> 2;
    const vf4* l4 = reinterpret_cast<const vf4*>(levels);
    __half2* h2 = reinterpret_cast<__half2*>(lev);
    for (int i = blockIdx.x * blockDim.x + threadIdx.x; i < n4; i += stride) {
        vf4 v = __builtin_nontemporal_load(&l4[i]);
        __half2 h0; h0.x = __float2half(v.x); h0.y = __float2half(v.y);
        __half2 h1; h1.x = __float2half(v.z); h1.y = __float2half(v.w);
        h2[2 * i]     = h0;
        h2[2 * i + 1] = h1;
    }
    for (int i = (n4 << 2) + blockIdx.x * blockDim.x + threadIdx.x; i < N; i += stride)
        lev[i] = __float2half(levels[i]);
}

// contrib[i] = sigmoid(attrs[i]·w + b) * (lev[i] - lev[parent]); root = levels[0]
// with sentinel p=N. attrs/parent are one-shot streams -> nontemporal.
__global__ void k_contrib(const float* __restrict__ attrs,
                          const float* __restrict__ weight,
                          const float* __restrict__ bias,
                          const float* __restrict__ levels,
                          const __half* __restrict__ lev,
                          const int*   __restrict__ parent,
                          SP* __restrict__ buf, int N) {
    float w0 = weight[0], w1 = weight[1], w2 = weight[2], w3 = weight[3];
    float w4 = weight[4], w5 = weight[5], w6 = weight[6], w7 = weight[7];
    float b = bias[0];
    int stride = gridDim.x * blockDim.x;
    const vf4* a4 = reinterpret_cast<const vf4*>(attrs);
    for (int i = blockIdx.x * blockDim.x + threadIdx.x; i < N; i += stride) {
        vf4 a0 = __builtin_nontemporal_load(&a4[2 * (size_t)i]);
        vf4 a1 = __builtin_nontemporal_load(&a4[2 * (size_t)i + 1]);
        float x = a0.x * w0 + a0.y * w1 + a0.z * w2 + a0.w * w3
                + a1.x * w4 + a1.y * w5 + a1.z * w6 + a1.w * w7 + b;
        float sg = 1.0f / (1.0f + __expf(-x));
        int p = __builtin_nontemporal_load(&parent[i]);
        float c = sg * (__half2float(lev[i]) - __half2float(lev[p]));  // lev[p]: L2-hot
        if (i == 0) stSP(&buf[0], levels[0], N);   // root: exact f32 level, sentinel
        else        stSP(&buf[i], c, p);
    }
}

// One ladder level [lo,hi): chase while the chain stays >= lo (parent index
// shrinks ~e x per hop), then add y16 of the already-exact lower levels
// (region <= lo*2 bytes, L2-resident). Bottom level (lo=0) exits only via the
// root sentinel p=N. fp16 rounding chains once per LEVEL, not per tree edge.
// Correct for any tree depth.
__global__ void k_level(const SP* __restrict__ buf,
                        __half* __restrict__ y16,
                        int lo, int hi, int N) {
    int i = lo + blockIdx.x * blockDim.x + threadIdx.x;
    if (i >= hi) return;
    float acc = 0.0f;
    int p = i;                       // first gather = coalesced self-read
    while (p >= lo && p < N) {
        SP w = ldSP(&buf[p]);
        acc += w.s;
        p = w.p;
    }
    if (p < lo) acc += __half2float(y16[p]);
    y16[i] = __float2half(acc);
}

// Gather pass A: nodes < seg only. Live y16 slice = 2 MB (half an XCD's L2
// -> stable residency; seg-1 lines never touched because loads are branch-
// predicated). Writes FULL 16B lines of f16 to scratch (seg-1 lanes = 0,
// don't-care) — no partial-line stores (R8's killer).
__global__ void k_gpassA(const __half* __restrict__ y,
                         const int*   __restrict__ pix,
                         __half*      __restrict__ scratch,
                         int M, int seg) {
    int stride = gridDim.x * blockDim.x;
    int M8 = M >> 3;
    const vi4* pix4 = reinterpret_cast<const vi4*>(pix);
    for (int g = blockIdx.x * blockDim.x + threadIdx.x; g < M8; g += stride) {
        vi4 p0 = __builtin_nontemporal_load(&pix4[2 * g]);
        vi4 p1 = __builtin_nontemporal_load(&pix4[2 * g + 1]);
        __half h[8];
        h[0] = (p0.x < seg) ? y[p0.x] : __half(0);
        h[1] = (p0.y < seg) ? y[p0.y] : __half(0);
        h[2] = (p0.z < seg) ? y[p0.z] : __half(0);
        h[3] = (p0.w < seg) ? y[p0.w] : __half(0);
        h[4] = (p1.x < seg) ? y[p1.x] : __half(0);
        h[5] = (p1.y < seg) ? y[p1.y] : __half(0);
        h[6] = (p1.z < seg) ? y[p1.z] : __half(0);
        h[7] = (p1.w < seg) ? y[p1.w] : __half(0);
        vi4 packed;
        packed.x = (int)(((unsigned)__half_as_ushort(h[1]) << 16) | __half_as_ushort(h[0]));
        packed.y = (int)(((unsigned)__half_as_ushort(h[3]) << 16) | __half_as_ushort(h[2]));
        packed.z = (int)(((unsigned)__half_as_ushort(h[5]) << 16) | __half_as_ushort(h[4]));
        packed.w = (int)(((unsigned)__half_as_ushort(h[7]) << 16) | __half_as_ushort(h[6]));
        __builtin_nontemporal_store(packed, reinterpret_cast<vi4*>(scratch + 8 * (size_t)g));
    }
    // tail: nothing (pass B handles i >= M8*8 completely)
}

// Gather pass B: nodes >= seg (other 2 MB slice), merge with pass-A carry,
// write full f32 lines. Carried f16 value is bit-exact (no extra rounding).
__global__ void k_gpassB(const __half* __restrict__ y,
                         const int*   __restrict__ pix,
                         const __half* __restrict__ scratch,
                         float*       __restrict__ out,
                         int M, int seg) {
    int stride = gridDim.x * blockDim.x;
    int M8 = M >> 3;
    const vi4* pix4 = reinterpret_cast<const vi4*>(pix);
    vf4* out4 = reinterpret_cast<vf4*>(out);
    for (int g = blockIdx.x * blockDim.x + threadIdx.x; g < M8; g += stride) {
        vi4 p0 = __builtin_nontemporal_load(&pix4[2 * g]);
        vi4 p1 = __builtin_nontemporal_load(&pix4[2 * g + 1]);
        vi4 c = __builtin_nontemporal_load(reinterpret_cast<const vi4*>(scratch + 8 * (size_t)g));
        __half ch[8];
        ch[0] = __ushort_as_half((unsigned short)( c.x        & 0xFFFF));
        ch[1] = __ushort_as_half((unsigned short)(((unsigned)c.x) >> 16));
        ch[2] = __ushort_as_half((unsigned short)( c.y        & 0xFFFF));
        ch[3] = __ushort_as_half((unsigned short)(((unsigned)c.y) >> 16));
        ch[4] = __ushort_as_half((unsigned short)( c.z        & 0xFFFF));
        ch[5] = __ushort_as_half((unsigned short)(((unsigned)c.z) >> 16));
        ch[6] = __ushort_as_half((unsigned short)( c.w        & 0xFFFF));
        ch[7] = __ushort_as_half((unsigned short)(((unsigned)c.w) >> 16));
        vf4 o0, o1;
        o0.x = __half2float((p0.x >= seg) ? y[p0.x] : ch[0]);
        o0.y = __half2float((p0.y >= seg) ? y[p0.y] : ch[1]);
        o0.z = __half2float((p0.z >= seg) ? y[p0.z] : ch[2]);
        o0.w = __half2float((p0.w >= seg) ? y[p0.w] : ch[3]);
        o1.x = __half2float((p1.x >= seg) ? y[p1.x] : ch[4]);
        o1.y = __half2float((p1.y >= seg) ? y[p1.y] : ch[5]);
        o1.z = __half2float((p1.z >= seg) ? y[p1.z] : ch[6]);
        o1.w = __half2float((p1.w >= seg) ? y[p1.w] : ch[7]);
        __builtin_nontemporal_store(o0, &out4[2 * g]);
        __builtin_nontemporal_store(o1, &out4[2 * g + 1]);
    }
    int tid = blockIdx.x * blockDim.x + threadIdx.x;
    for (int i = (M8 << 3) + tid; i < M; i += stride)
        out[i] = __half2float(y[pix[i]]);   // tail handles both segments
}

extern "C" void kernel_launch(void* const* d_in, const int* in_sizes, int n_in,
                              void* d_out, int out_size, void* d_ws, size_t ws_size,
                              hipStream_t stream) {
    const float* attrs  = (const float*)d_in[0];
    const float* weight = (const float*)d_in[1];
    const float* bias   = (const float*)d_in[2];
    const float* levels = (const float*)d_in[3];
    const int*   parent = (const int*)d_in[4];
    const int*   pix    = (const int*)d_in[5];
    float* out = (float*)d_out;

    const int N = in_sizes[3];     // 2,000,000 nodes
    const int M = out_size;        // H*W pixels

    SP*     buf     = (SP*)d_ws;               // 16 MB packed {contrib, parent}
    __half* y16     = (__half*)(buf + N);      //  4 MB node outputs (fp16)
    __half* lev16   = (__half*)(y16 + N);      //  4 MB levels (fp16)
    __half* scratch = (__half*)(lev16 + N);    //  8.4 MB gather carry (f16/pixel)

    const int BLK = 256;
    #define CDIV(a,b) (((a)+(b)-1)/(b))

    k_lev16  <<<1024, BLK, 0, stream>>>(levels, lev16, N);
    k_contrib<<<2048, BLK, 0, stream>>>(attrs, weight, bias, levels, lev16, parent, buf, N);

    // Geometric ladder, bottom-up (R7's proven 4-level split).
    const int T1 = 32768, T2 = 524288, T3 = 1048576;
    k_level<<<CDIV(T1,      BLK), BLK, 0, stream>>>(buf, y16, 0,  T1, N);
    k_level<<<CDIV(T2 - T1, BLK), BLK, 0, stream>>>(buf, y16, T1, T2, N);
    k_level<<<CDIV(T3 - T2, BLK), BLK, 0, stream>>>(buf, y16, T2, T3, N);
    k_level<<<CDIV(N  - T3, BLK), BLK, 0, stream>>>(buf, y16, T3, N,  N);

    // Two-pass pixel gather: each pass's live y16 slice is 2 MB -> L2-stable.
    k_gpassA<<<2048, BLK, 0, stream>>>(y16, pix, scratch, M, T3);
    k_gpassB<<<2048, BLK, 0, stream>>>(y16, pix, scratch, out, M, T3);
}

// Round 11
// 96.111 us; speedup vs baseline: 1.0671x; 1.0671x over previous
//
#include <hip/hip_runtime.h>
#include <hip/hip_fp16.h>

// Clang native vector types — required by __builtin_nontemporal_* (HIP's
// float4/int4 are classes, which the builtin rejects).
typedef float    vf4 __attribute__((ext_vector_type(4)));
typedef int      vi4 __attribute__((ext_vector_type(4)));
typedef unsigned vu4 __attribute__((ext_vector_type(4)));

// Packed node record: path-segment sum s and jump pointer p in 8 bytes,
// so each random gather touches exactly one cache line.
struct SP { float s; int p; };

__device__ __forceinline__ SP ldSP(const SP* __restrict__ ptr) {
    float2 v = *reinterpret_cast<const float2*>(ptr);
    SP r; r.s = v.x; r.p = __float_as_int(v.y);
    return r;
}
__device__ __forceinline__ void stSP(SP* __restrict__ ptr, float s, int p) {
    float2 v; v.x = s; v.y = __int_as_float(p);
    *reinterpret_cast<float2*>(ptr) = v;
}

// Build a raw-buffer SRD (stride=0, num_records=bytes, word3=0x20000).
__device__ __forceinline__ vu4 make_srd(const void* p, unsigned bytes) {
    union { const void* p; unsigned u[2]; } u; u.p = p;
    vu4 s; s.x = u.u[0]; s.y = u.u[1] & 0xFFFFu; s.z = bytes; s.w = 0x00020000u;
    return s;
}

// levels -> fp16 table (4 MB, L2-resident) so contrib's random parent-level
// gathers stop missing. f32 source streamed nontemporally.
__global__ void k_lev16(const float* __restrict__ levels,
                        __half* __restrict__ lev, int N) {
    int stride = gridDim.x * blockDim.x;
    int n4 = N >> 2;
    const vf4* l4 = reinterpret_cast<const vf4*>(levels);
    __half2* h2 = reinterpret_cast<__half2*>(lev);
    for (int i = blockIdx.x * blockDim.x + threadIdx.x; i < n4; i += stride) {
        vf4 v = __builtin_nontemporal_load(&l4[i]);
        __half2 h0; h0.x = __float2half(v.x); h0.y = __float2half(v.y);
        __half2 h1; h1.x = __float2half(v.z); h1.y = __float2half(v.w);
        h2[2 * i]     = h0;
        h2[2 * i + 1] = h1;
    }
    for (int i = (n4 << 2) + blockIdx.x * blockDim.x + threadIdx.x; i < N; i += stride)
        lev[i] = __float2half(levels[i]);
}

// contrib[i] = sigmoid(attrs[i]·w + b) * (lev[i] - lev[parent]); root = levels[0]
// with sentinel p=N. attrs/parent are one-shot streams -> nontemporal.
__global__ void k_contrib(const float* __restrict__ attrs,
                          const float* __restrict__ weight,
                          const float* __restrict__ bias,
                          const float* __restrict__ levels,
                          const __half* __restrict__ lev,
                          const int*   __restrict__ parent,
                          SP* __restrict__ buf, int N) {
    float w0 = weight[0], w1 = weight[1], w2 = weight[2], w3 = weight[3];
    float w4 = weight[4], w5 = weight[5], w6 = weight[6], w7 = weight[7];
    float b = bias[0];
    int stride = gridDim.x * blockDim.x;
    const vf4* a4 = reinterpret_cast<const vf4*>(attrs);
    for (int i = blockIdx.x * blockDim.x + threadIdx.x; i < N; i += stride) {
        vf4 a0 = __builtin_nontemporal_load(&a4[2 * (size_t)i]);
        vf4 a1 = __builtin_nontemporal_load(&a4[2 * (size_t)i + 1]);
        float x = a0.x * w0 + a0.y * w1 + a0.z * w2 + a0.w * w3
                + a1.x * w4 + a1.y * w5 + a1.z * w6 + a1.w * w7 + b;
        float sg = 1.0f / (1.0f + __expf(-x));
        int p = __builtin_nontemporal_load(&parent[i]);
        float c = sg * (__half2float(lev[i]) - __half2float(lev[p]));  // lev[p]: L2-hot
        if (i == 0) stSP(&buf[0], levels[0], N);   // root: exact f32 level, sentinel
        else        stSP(&buf[i], c, p);
    }
}

// One ladder level [lo,hi): chase while the chain stays >= lo (parent index
// shrinks ~e x per hop), then add y16 of the already-exact lower levels
// (region <= lo*2 bytes, L2-resident). Bottom level (lo=0) exits only via the
// root sentinel p=N. fp16 rounding chains once per LEVEL, not per tree edge.
// Correct for any tree depth.
__global__ void k_level(const SP* __restrict__ buf,
                        __half* __restrict__ y16,
                        int lo, int hi, int N) {
    int i = lo + blockIdx.x * blockDim.x + threadIdx.x;
    if (i >= hi) return;
    float acc = 0.0f;
    int p = i;                       // first gather = coalesced self-read
    while (p >= lo && p < N) {
        SP w = ldSP(&buf[p]);
        acc += w.s;
        p = w.p;
    }
    if (p < lo) acc += __half2float(y16[p]);
    y16[i] = __float2half(acc);
}

// out[pixel] = y16[pixel_node[pixel]]. pix loads and out stores use
// buffer ops with sc1+nt (system-scope streaming: bypass L2) so the 4 MB y16
// array keeps L2 residency; y16 loads allocate normally. Straight-line: one
// thread = 4 pixels, grid sized exactly (no loop -> asm reg reuse is safe;
// trailing vmcnt(0) covers the in-flight store at kernel end).
__global__ void k_gather(const __half* __restrict__ y,
                         const int*   __restrict__ pix,
                         float*       __restrict__ out, int M) {
    int g = blockIdx.x * blockDim.x + threadIdx.x;
    int M4 = M >> 2;
    if (g < M4) {
        vu4 srdP = make_srd(pix, (unsigned)M * 4u);
        vu4 srdO = make_srd(out, (unsigned)M * 4u);
        unsigned voff = (unsigned)g * 16u;
        vi4 p;
        asm volatile("buffer_load_dwordx4 %0, %1, %2, 0 offen sc1 nt\n\t"
                     "s_waitcnt vmcnt(0)"
                     : "=v"(p) : "v"(voff), "s"(srdP) : "memory");
        vf4 o;
        o.x = __half2float(y[p.x]);
        o.y = __half2float(y[p.y]);
        o.z = __half2float(y[p.z]);
        o.w = __half2float(y[p.w]);
        asm volatile("buffer_store_dwordx4 %0, %1, %2, 0 offen sc1 nt"
                     :: "v"(__builtin_bit_cast(vi4, o)), "v"(voff), "s"(srdO)
                     : "memory");
    }
    // tail (M % 4 != 0): plain path. Not taken at 2048x2048.
    int stride = gridDim.x * blockDim.x;
    for (int i = (M4 << 2) + g; i < M; i += stride)
        out[i] = __half2float(y[pix[i]]);
    asm volatile("s_waitcnt vmcnt(0)" ::: "memory");
}

extern "C" void kernel_launch(void* const* d_in, const int* in_sizes, int n_in,
                              void* d_out, int out_size, void* d_ws, size_t ws_size,
                              hipStream_t stream) {
    const float* attrs  = (const float*)d_in[0];
    const float* weight = (const float*)d_in[1];
    const float* bias   = (const float*)d_in[2];
    const float* levels = (const float*)d_in[3];
    const int*   parent = (const int*)d_in[4];
    const int*   pix    = (const int*)d_in[5];
    float* out = (float*)d_out;

    const int N = in_sizes[3];     // 2,000,000 nodes
    const int M = out_size;        // H*W pixels

    SP*     buf   = (SP*)d_ws;                // 16 MB packed {contrib, parent}
    __half* y16   = (__half*)(buf + N);       //  4 MB node outputs (fp16)
    __half* lev16 = (__half*)(y16 + N);       //  4 MB levels (fp16)

    const int BLK = 256;
    #define CDIV(a,b) (((a)+(b)-1)/(b))

    k_lev16  <<<1024, BLK, 0, stream>>>(levels, lev16, N);
    k_contrib<<<2048, BLK, 0, stream>>>(attrs, weight, bias, levels, lev16, parent, buf, N);

    // Geometric ladder, bottom-up (R7's proven 4-level split).
    const int T1 = 32768, T2 = 524288, T3 = 1048576;
    k_level<<<CDIV(T1,      BLK), BLK, 0, stream>>>(buf, y16, 0,  T1, N);
    k_level<<<CDIV(T2 - T1, BLK), BLK, 0, stream>>>(buf, y16, T1, T2, N);
    k_level<<<CDIV(T3 - T2, BLK), BLK, 0, stream>>>(buf, y16, T2, T3, N);
    k_level<<<CDIV(N  - T3, BLK), BLK, 0, stream>>>(buf, y16, T3, N,  N);

    // Pixel gather: streams bypass L2 (sc1 nt), y16 keeps residency.
    k_gather<<<CDIV(M / 4, BLK), BLK, 0, stream>>>(y16, pix, out, M);
}